// Round 9
// baseline (73.165 us; speedup 1.0000x reference)
//
#include <hip/hip_runtime.h>
#include <hip/hip_bf16.h>

#define NN 300
#define TB 16
#define TTOT 4096
#define MPAD 320            // padded M/K (20 x 16 / 10 x 32)
#define NKS 10
#define TC 32               // t-chunk per block
#define NTC (TTOT / TC)     // 128
#define LDX 328             // LDS row stride in ushort (656 B, 16B-aligned rows)
#define FBS 36              // flush-buffer row stride in dwords (144 B, 16B-aligned)
#define BNT ((size_t)TB * NN * TTOT)

typedef __attribute__((ext_vector_type(8))) short short8;
typedef __attribute__((ext_vector_type(4))) float f32x4;

static __device__ __forceinline__ ushort f2bf(float f) {
    __hip_bfloat16 h = __float2bfloat16(f);
    return *reinterpret_cast<ushort*>(&h);
}
static __device__ __forceinline__ float bf2f(ushort u) {
    unsigned v = ((unsigned)u) << 16;
    return __uint_as_float(v);
}

// ws layout: WebP @0 : 20*10*512 ushorts = 204800 B ; scal @204800 : 320*5*4 = 6400 B
#define OFF_SCAL 204800

// ---------------- prep: packed bf16 W_e fragments + per-row scalars ----------------
// WebP[mb(20)][ks(10)][lane(64)][e(8)] ; elem = W_e[i = mb*16 + (l&15)][k = ks*32 + (l>>4)*8 + e]
__global__ __launch_bounds__(64) void lic_prep(
    const float* __restrict__ sc, const float* __restrict__ se,
    const float* __restrict__ mc, const float* __restrict__ me,
    const float* __restrict__ E,  const float* __restrict__ bias,
    const float* __restrict__ tau,
    ushort* __restrict__ WebP, float* __restrict__ scal /* [320][5] */) {
    const int i = blockIdx.x;       // 0..319
    const int lane = threadIdx.x;
    float a = 0.f, s = 0.f, r = 0.f;
    for (int j = lane; j < MPAD; j += 64) {
        float we = 0.f;
        if (i < NN && j < NN) {
            float wc = sc[i * NN + j] * (mc[i * NN + j] * 0.01f);
            a += wc * E[i * NN + j];
            s += wc;
            we = se[i * NN + j] * ((me[i * NN + j] + me[j * NN + i]) * 0.01f);
            r += we;
        }
        const int mb = i >> 4, ri = i & 15;
        const int kb = j >> 5, ko = (j >> 3) & 3, e = j & 7;
        WebP[((size_t)(mb * NKS + kb) * 64 + (ri + ko * 16)) * 8 + e] = f2bf(we);
    }
    #pragma unroll
    for (int o = 32; o > 0; o >>= 1) {
        a += __shfl_down(a, o);
        s += __shfl_down(s, o);
        r += __shfl_down(r, o);
    }
    if (lane == 0) {
        float* p = &scal[i * 5];
        p[0] = a;
        p[1] = s;
        p[2] = r;
        p[3] = (i < NN) ? (0.01f / tau[i]) : 0.f;
        p[4] = (i < NN) ? bias[i] : 0.f;
    }
}

// ---------------- fused: stage x tile -> 5 pipelined fc-passes -> full-line flush ----------------
__global__ __launch_bounds__(256, 4) void lic_fused(
    const float* __restrict__ input, const float* __restrict__ hidden,
    const ushort* __restrict__ WebP, const float* __restrict__ scal,
    float* __restrict__ out) {
    __shared__ ushort xs[TC][LDX];          // x (time-shifted, bf16), rows t, cols j
    __shared__ float fbuf[4][16 * FBS];     // per-wave store-staging (2304 B each)

    const int nwg = TB * NTC;               // 2048
    const int blk0 = blockIdx.x;
    const int blk = (blk0 & 7) * (nwg / 8) + (blk0 >> 3);   // XCD chunking (bijective)
    const int b  = blk / NTC;
    const int tc = blk % NTC;
    const int t0 = tc * TC;
    const int tid = threadIdx.x;
    const size_t bOff = (size_t)b * NN * TTOT;
    const float* hb = hidden + bOff;

    const int l  = tid & 63;
    const int w  = tid >> 6;                // wave 0..3 -> i base = w*80
    const int lo = l & 15, hi = l >> 4;
    const int iBase = w * 80;
    float* fb = &fbuf[w][0];
    const int rrow = l >> 3;                // 0..7
    const int rcol = (l & 7) * 4;           // 0,4,...,28
    const f32x4 vzero = (f32x4){0.f, 0.f, 0.f, 0.f};

    // ---- issue W-stream ring + first input tile BEFORE staging barrier ----
    const ushort* Wst = WebP + (size_t)(iBase >> 4) * (NKS * 512) + l * 8;
    short8 wring[4];
    #pragma unroll
    for (int p2 = 0; p2 < 4; ++p2)
        wring[p2] = *(const short8*)(Wst + (size_t)p2 * 512);

    f32x4 inpA[2], inpB[2];
    auto loadInp = [&](int fc, f32x4* dst) {
        const int i = iBase + fc * 16 + lo;
        if (i < NN) {
            const float* ip = input + bOff + (size_t)i * TTOT + t0 + hi * 4;
            dst[0] = *(const f32x4*)ip;
            dst[1] = *(const f32x4*)(ip + 16);
        } else {
            dst[0] = vzero; dst[1] = vzero;
        }
    };
    loadInp(0, inpA);

    // ---- stage x[b, 0..319, t0..t0+31] into LDS (bf16, shift baked in) ----
    {
        const int t4 = tid & 7;             // float4 slot within 32-t row
        const int jl = tid >> 3;            // 32 j rows per iteration
        #pragma unroll
        for (int it = 0; it < 10; ++it) {
            const int j = jl + it * 32;     // 0..319
            f32x4 hv = (f32x4){0.f, 0.f, 0.f, 0.f};
            float x0 = 0.f;
            if (j < NN) {
                const float* hp = hb + (size_t)j * TTOT + t0 + t4 * 4;
                hv = *(const f32x4*)hp;
                if (t4 == 0 && t0 > 0) x0 = hp[-1];
            }
            if (t4 == 0) xs[0][j] = f2bf(x0);
            #pragma unroll
            for (int r = 0; r < 3; ++r) xs[t4 * 4 + r + 1][j] = f2bf(hv[r]);
            if (t4 < 7) xs[t4 * 4 + 4][j] = f2bf(hv[3]);
        }
    }
    __syncthreads();

    #pragma unroll
    for (int fc = 0; fc < 5; ++fc) {
        const f32x4* curInp = (fc & 1) ? inpB : inpA;
        f32x4*       nxtInp = (fc & 1) ? inpA : inpB;
        if (fc + 1 < 5) loadInp(fc + 1, nxtInp);

        const int i = iBase + fc * 16 + lo;
        const float* p = &scal[i * 5];
        const float sA = p[0], sS = p[1], sR = p[2], sD = p[3], sB = p[4];

        // ---- GEMM pass: flat W-stream ring (depth 4) + xf ring (depth 1) ----
        f32x4 acc0 = vzero, acc1 = vzero;
        short8 xa = *(const short8*)&xs[lo][hi * 8];
        short8 xb = *(const short8*)&xs[16 + lo][hi * 8];
        #pragma unroll
        for (int ks = 0; ks < NKS; ++ks) {
            const int g = fc * NKS + ks;
            const short8 wf = wring[g & 3];
            if (g + 4 < 5 * NKS)
                wring[g & 3] = *(const short8*)(Wst + (size_t)(g + 4) * 512);
            short8 na, nb;
            if (ks + 1 < NKS) {
                na = *(const short8*)&xs[lo][(ks + 1) * 32 + hi * 8];
                nb = *(const short8*)&xs[16 + lo][(ks + 1) * 32 + hi * 8];
            }
            acc0 = __builtin_amdgcn_mfma_f32_16x16x32_bf16(xa, wf, acc0, 0, 0, 0);
            acc1 = __builtin_amdgcn_mfma_f32_16x16x32_bf16(xb, wf, acc1, 0, 0, 0);
            if (ks + 1 < NKS) { xa = na; xb = nb; }
        }

        // ---- epilogue compute: C^T layout (t = fr*16 + hi*4 + rr, col i) ----
        f32x4 vmu[2], vch[2], vel[2];
        #pragma unroll
        for (int fr = 0; fr < 2; ++fr) {
            const f32x4 accv = fr ? acc1 : acc0;
            const int tb = fr * 16 + hi * 4;
            const f32x4 inv = curInp[fr];
            #pragma unroll
            for (int rr = 0; rr < 4; ++rr) {
                const float x = bf2f(xs[tb + rr][i]);
                const float elec = accv[rr] - sR * x;
                const float chem = (sA - x * sS) * fmaxf(x, 0.f);
                vel[fr][rr] = elec;
                vch[fr][rr] = chem;
                vmu[fr][rr] = sD * (chem + elec + sB + inv[rr] - x) + x;
            }
        }

        // ---- flush: LDS transpose -> 8 rows x 128B full-line NT stores ----
        const int i0 = iBase + fc * 16;
        const int ia = i0 + rrow, ic = i0 + 8 + rrow;
        float* outp[3] = {out, out + BNT, out + 2 * BNT};
        f32x4* vals[3][2] = {{&vmu[0], &vmu[1]}, {&vch[0], &vch[1]}, {&vel[0], &vel[1]}};
        #pragma unroll
        for (int ov = 0; ov < 3; ++ov) {
            *(f32x4*)&fb[lo * FBS + hi * 4]      = *vals[ov][0];
            *(f32x4*)&fb[lo * FBS + 16 + hi * 4] = *vals[ov][1];
            const f32x4 s0 = *(const f32x4*)&fb[rrow * FBS + rcol];
            const f32x4 s1 = *(const f32x4*)&fb[(8 + rrow) * FBS + rcol];
            if (ia < NN)
                __builtin_nontemporal_store(s0, (f32x4*)&outp[ov][bOff + (size_t)ia * TTOT + t0 + rcol]);
            if (ic < NN)
                __builtin_nontemporal_store(s1, (f32x4*)&outp[ov][bOff + (size_t)ic * TTOT + t0 + rcol]);
        }
    }
}

extern "C" void kernel_launch(void* const* d_in, const int* in_sizes, int n_in,
                              void* d_out, int out_size, void* d_ws, size_t ws_size,
                              hipStream_t stream) {
    const float* input  = (const float*)d_in[0];
    const float* hidden = (const float*)d_in[1];
    const float* sc     = (const float*)d_in[2];
    const float* se     = (const float*)d_in[3];
    const float* mc     = (const float*)d_in[4];
    const float* me     = (const float*)d_in[5];
    const float* E      = (const float*)d_in[6];
    const float* bias   = (const float*)d_in[7];
    const float* tau    = (const float*)d_in[8];
    float* out = (float*)d_out;

    ushort* WebP = (ushort*)d_ws;
    float*  scal = (float*)((char*)d_ws + OFF_SCAL);

    lic_prep<<<MPAD, 64, 0, stream>>>(sc, se, mc, me, E, bias, tau, WebP, scal);
    lic_fused<<<TB * NTC, 256, 0, stream>>>(input, hidden, WebP, scal, out);
}